// Round 1
// baseline (254.313 us; speedup 1.0000x reference)
//
#include <hip/hip_runtime.h>

// MultiHeadAttn: B=2, T=2048, D=1024, H=16, dh=64
// inputs: Q_seq,K_seq,V_seq [2,2048,1024] f32; Q_len,V_len [2,1] i32; WQ,WK,WV [1024,1024] f32
// output: [2,2048,1024] f32

using short8   = __attribute__((ext_vector_type(8))) short;
using floatx4  = __attribute__((ext_vector_type(4))) float;
using ushort4v = __attribute__((ext_vector_type(4))) unsigned short;

__device__ __forceinline__ unsigned short f2bf(float f) {
    unsigned int u = __builtin_bit_cast(unsigned int, f);
    u += 0x7fffu + ((u >> 16) & 1u);   // round-to-nearest-even
    return (unsigned short)(u >> 16);
}

// ---------------------------------------------------------------------------
// Kernel 1: W [1024][1024] f32  ->  W^T [1024][1024] bf16 (z = 0,1,2)
// ---------------------------------------------------------------------------
__global__ __launch_bounds__(256) void wt_kernel(
    const float* __restrict__ W0, const float* __restrict__ W1,
    const float* __restrict__ W2, unsigned short* __restrict__ out)
{
    __shared__ float tile[64][65];
    int z = blockIdx.z;
    const float* W = (z == 0) ? W0 : ((z == 1) ? W1 : W2);
    unsigned short* O = out + (size_t)z * 1048576u;
    int r0 = blockIdx.y * 64, c0 = blockIdx.x * 64;
    int t = threadIdx.x;
#pragma unroll
    for (int i = 0; i < 16; i++) {
        int idx = t + i * 256; int r = idx >> 6, c = idx & 63;
        tile[r][c] = W[(size_t)(r0 + r) * 1024 + c0 + c];
    }
    __syncthreads();
#pragma unroll
    for (int i = 0; i < 16; i++) {
        int idx = t + i * 256; int c = idx >> 6, r = idx & 63;
        O[(size_t)(c0 + c) * 1024 + r0 + r] = f2bf(tile[r][c]);
    }
}

// ---------------------------------------------------------------------------
// Kernel 2: projection GEMM  C[4096,1024] = A[4096,1024] @ W[1024,1024]
//   z=0 -> q (row-major bf16), z=1 -> k (row-major bf16),
//   z=2 -> vT layout [(b*1024 + h*64+d)][t] bf16
// 128x128 tile, BK=32, 4 waves (2x2), each wave 64x64 (4x4 frags 16x16x32)
// ---------------------------------------------------------------------------
__global__ __launch_bounds__(256) void proj_kernel(
    const float* __restrict__ Qs, const float* __restrict__ Ks,
    const float* __restrict__ Vs, const unsigned short* __restrict__ wt,
    unsigned short* __restrict__ q, unsigned short* __restrict__ k,
    unsigned short* __restrict__ vT)
{
    __shared__ alignas(16) unsigned short As[128][40];
    __shared__ alignas(16) unsigned short Bs[128][40];

    int z = blockIdx.z;
    const float* A = (z == 0) ? Qs : ((z == 1) ? Ks : Vs);
    const unsigned short* Bt = wt + (size_t)z * 1048576u;

    int tid = threadIdx.x;
    int m0 = blockIdx.y * 128, n0 = blockIdx.x * 128;
    int w = tid >> 6, lane = tid & 63, g = lane >> 4, lr = lane & 15;
    int wr = w >> 1, wc = w & 1;

    floatx4 acc[4][4];
#pragma unroll
    for (int m = 0; m < 4; m++)
#pragma unroll
        for (int n = 0; n < 4; n++) acc[m][n] = floatx4{0.f, 0.f, 0.f, 0.f};

    int arow = tid >> 1, ahalf = tid & 1;

    for (int kb = 0; kb < 1024; kb += 32) {
        // stage A (fp32 -> bf16): 128x32
        {
            const float* p = A + (size_t)(m0 + arow) * 1024 + kb + ahalf * 16;
            float f[16];
#pragma unroll
            for (int i = 0; i < 4; i++) {
                float4 v = *reinterpret_cast<const float4*>(p + i * 4);
                f[i * 4 + 0] = v.x; f[i * 4 + 1] = v.y;
                f[i * 4 + 2] = v.z; f[i * 4 + 3] = v.w;
            }
            short8 h0, h1;
#pragma unroll
            for (int j = 0; j < 8; j++) h0[j] = (short)f2bf(f[j]);
#pragma unroll
            for (int j = 0; j < 8; j++) h1[j] = (short)f2bf(f[8 + j]);
            *reinterpret_cast<short8*>(&As[arow][ahalf * 16]) = h0;
            *reinterpret_cast<short8*>(&As[arow][ahalf * 16 + 8]) = h1;
        }
        // stage B^T (bf16 copy): 128 rows x 32 k
#pragma unroll
        for (int i = 0; i < 2; i++) {
            int ci = tid + i * 256; int row = ci >> 2, piece = ci & 3;
            *reinterpret_cast<short8*>(&Bs[row][piece * 8]) =
                *reinterpret_cast<const short8*>(Bt + (size_t)(n0 + row) * 1024 + kb + piece * 8);
        }
        __syncthreads();

        short8 af[4], bf[4];
#pragma unroll
        for (int m = 0; m < 4; m++)
            af[m] = *reinterpret_cast<const short8*>(&As[wr * 64 + m * 16 + lr][g * 8]);
#pragma unroll
        for (int n = 0; n < 4; n++)
            bf[n] = *reinterpret_cast<const short8*>(&Bs[wc * 64 + n * 16 + lr][g * 8]);
#pragma unroll
        for (int m = 0; m < 4; m++)
#pragma unroll
            for (int n = 0; n < 4; n++)
                acc[m][n] = __builtin_amdgcn_mfma_f32_16x16x32_bf16(af[m], bf[n], acc[m][n], 0, 0, 0);
        __syncthreads();
    }

    // epilogue
    if (z < 2) {
        unsigned short* out = (z == 0) ? q : k;
#pragma unroll
        for (int m = 0; m < 4; m++) {
            int row0 = m0 + wr * 64 + m * 16 + g * 4;
#pragma unroll
            for (int n = 0; n < 4; n++) {
                int col = n0 + wc * 64 + n * 16 + lr;
#pragma unroll
                for (int r = 0; r < 4; r++)
                    out[(size_t)(row0 + r) * 1024 + col] = f2bf(acc[m][n][r]);
            }
        }
    } else {
#pragma unroll
        for (int m = 0; m < 4; m++) {
            int row0 = m0 + wr * 64 + m * 16 + g * 4;
            int bb = row0 >> 11, t0 = row0 & 2047;
#pragma unroll
            for (int n = 0; n < 4; n++) {
                int col = n0 + wc * 64 + n * 16 + lr;
                ushort4v pk;
#pragma unroll
                for (int r = 0; r < 4; r++) pk[r] = f2bf(acc[m][n][r]);
                *reinterpret_cast<ushort4v*>(vT + (size_t)(bb * 1024 + col) * 2048 + t0) = pk;
            }
        }
    }
}

// ---------------------------------------------------------------------------
// Kernel 3: flash attention.
// grid (16 q-tiles, 32 bh), 256 threads. Each wave: 32 q rows (2 row-blocks).
// KVBLK=64. Online softmax; P via per-wave LDS round trip.
// ---------------------------------------------------------------------------
__global__ __launch_bounds__(256) void attn_kernel(
    const unsigned short* __restrict__ q, const unsigned short* __restrict__ k,
    const unsigned short* __restrict__ vT, const int* __restrict__ Q_len,
    const int* __restrict__ V_len, float* __restrict__ out)
{
    __shared__ alignas(16) unsigned short ks[64][72];
    __shared__ alignas(16) unsigned short vs[64][72];
    __shared__ alignas(16) unsigned short ps[4][32][72];

    int tid = threadIdx.x, w = tid >> 6, lane = tid & 63, g = lane >> 4, lr = lane & 15;
    int qt = blockIdx.x * 128;
    int bh = blockIdx.y; int b = bh >> 4, h = bh & 15;
    int qlen = Q_len[b], vlen = V_len[b];

    // Q fragments, held for the whole kernel
    short8 qf[2][2];
#pragma unroll
    for (int rb = 0; rb < 2; rb++) {
        int qrow = qt + w * 32 + rb * 16 + lr;
        const unsigned short* qp = q + (size_t)(b * 2048 + qrow) * 1024 + h * 64;
#pragma unroll
        for (int kc = 0; kc < 2; kc++)
            qf[rb][kc] = *reinterpret_cast<const short8*>(qp + kc * 32 + g * 8);
    }

    floatx4 of[2][4];
    float m_r[2][4], l_r[2][4];
#pragma unroll
    for (int rb = 0; rb < 2; rb++) {
#pragma unroll
        for (int db = 0; db < 4; db++) of[rb][db] = floatx4{0.f, 0.f, 0.f, 0.f};
#pragma unroll
        for (int r = 0; r < 4; r++) { m_r[rb][r] = -3.0e38f; l_r[rb][r] = 0.f; }
    }

    for (int kt = 0; kt < 2048; kt += 64) {
        // stage K tile [64 key][64 dh] and V^T tile [64 d][64 key]
#pragma unroll
        for (int i = 0; i < 2; i++) {
            int ci = tid + i * 256; int row = ci >> 3, piece = ci & 7;
            *reinterpret_cast<short8*>(&ks[row][piece * 8]) =
                *reinterpret_cast<const short8*>(k + (size_t)(b * 2048 + kt + row) * 1024 + h * 64 + piece * 8);
            *reinterpret_cast<short8*>(&vs[row][piece * 8]) =
                *reinterpret_cast<const short8*>(vT + (size_t)(b * 1024 + h * 64 + row) * 2048 + kt + piece * 8);
        }
        __syncthreads();

        short8 kf[4][2], vf[4][2];
#pragma unroll
        for (int kb = 0; kb < 4; kb++)
#pragma unroll
            for (int kc = 0; kc < 2; kc++)
                kf[kb][kc] = *reinterpret_cast<const short8*>(&ks[kb * 16 + lr][kc * 32 + g * 8]);
#pragma unroll
        for (int db = 0; db < 4; db++)
#pragma unroll
            for (int kc = 0; kc < 2; kc++)
                vf[db][kc] = *reinterpret_cast<const short8*>(&vs[db * 16 + lr][kc * 32 + g * 8]);

#pragma unroll
        for (int rb = 0; rb < 2; rb++) {
            // S = Q K^T / 8 - mask   (C layout: row=g*4+r -> q, col=lr -> key)
            floatx4 sv[4];
#pragma unroll
            for (int kb = 0; kb < 4; kb++) {
                floatx4 a = floatx4{0.f, 0.f, 0.f, 0.f};
#pragma unroll
                for (int kc = 0; kc < 2; kc++)
                    a = __builtin_amdgcn_mfma_f32_16x16x32_bf16(qf[rb][kc], kf[kb][kc], a, 0, 0, 0);
                float pen = ((kt + kb * 16 + lr) >= vlen) ? 1.0e12f : 0.f;
#pragma unroll
                for (int r = 0; r < 4; r++) sv[kb][r] = a[r] * 0.125f - pen;
            }
            // row max across 16 cols (16-lane groups)
            float lm[4];
#pragma unroll
            for (int r = 0; r < 4; r++)
                lm[r] = fmaxf(fmaxf(sv[0][r], sv[1][r]), fmaxf(sv[2][r], sv[3][r]));
#pragma unroll
            for (int off = 8; off >= 1; off >>= 1)
#pragma unroll
                for (int r = 0; r < 4; r++)
                    lm[r] = fmaxf(lm[r], __shfl_xor(lm[r], off, 16));
            float al[4];
#pragma unroll
            for (int r = 0; r < 4; r++) {
                float mn = fmaxf(m_r[rb][r], lm[r]);
                al[r] = __expf(m_r[rb][r] - mn);
                m_r[rb][r] = mn;
            }
            // p = exp(s - m)
#pragma unroll
            for (int kb = 0; kb < 4; kb++)
#pragma unroll
                for (int r = 0; r < 4; r++)
                    sv[kb][r] = __expf(sv[kb][r] - m_r[rb][r]);
            // row sum
            float rs[4];
#pragma unroll
            for (int r = 0; r < 4; r++)
                rs[r] = (sv[0][r] + sv[1][r]) + (sv[2][r] + sv[3][r]);
#pragma unroll
            for (int off = 8; off >= 1; off >>= 1)
#pragma unroll
                for (int r = 0; r < 4; r++)
                    rs[r] += __shfl_xor(rs[r], off, 16);
#pragma unroll
            for (int r = 0; r < 4; r++)
                l_r[rb][r] = l_r[rb][r] * al[r] + rs[r];
            // rescale O
#pragma unroll
            for (int db = 0; db < 4; db++)
#pragma unroll
                for (int r = 0; r < 4; r++)
                    of[rb][db][r] *= al[r];
            // P -> bf16 -> per-wave LDS (re-layout for A-operand)
#pragma unroll
            for (int kb = 0; kb < 4; kb++)
#pragma unroll
                for (int r = 0; r < 4; r++)
                    ps[w][rb * 16 + g * 4 + r][kb * 16 + lr] = f2bf(sv[kb][r]);
        }

        // PV: O += P @ V
#pragma unroll
        for (int rb = 0; rb < 2; rb++) {
            short8 pf[2];
#pragma unroll
            for (int kc = 0; kc < 2; kc++)
                pf[kc] = *reinterpret_cast<const short8*>(&ps[w][rb * 16 + lr][kc * 32 + g * 8]);
#pragma unroll
            for (int db = 0; db < 4; db++)
#pragma unroll
                for (int kc = 0; kc < 2; kc++)
                    of[rb][db] = __builtin_amdgcn_mfma_f32_16x16x32_bf16(pf[kc], vf[db][kc], of[rb][db], 0, 0, 0);
        }
        __syncthreads();
    }

    // epilogue: O /= l, query-length mask, write fp32
#pragma unroll
    for (int rb = 0; rb < 2; rb++) {
#pragma unroll
        for (int r = 0; r < 4; r++) {
            int qrow = qt + w * 32 + rb * 16 + g * 4 + r;
            float qm = (qrow < qlen) ? (1.f / l_r[rb][r]) : 0.f;
#pragma unroll
            for (int db = 0; db < 4; db++)
                out[(size_t)(b * 2048 + qrow) * 1024 + h * 64 + db * 16 + lr] =
                    of[rb][db][r] * qm;
        }
    }
}

// ---------------------------------------------------------------------------
extern "C" void kernel_launch(void* const* d_in, const int* in_sizes, int n_in,
                              void* d_out, int out_size, void* d_ws, size_t ws_size,
                              hipStream_t stream)
{
    const float* Q_seq = (const float*)d_in[0];
    const float* K_seq = (const float*)d_in[1];
    const float* V_seq = (const float*)d_in[2];
    const int*   Q_len = (const int*)d_in[3];
    const int*   V_len = (const int*)d_in[4];
    const float* WQ    = (const float*)d_in[5];
    const float* WK    = (const float*)d_in[6];
    const float* WV    = (const float*)d_in[7];
    float* outp = (float*)d_out;

    // workspace layout (bf16 elems): Wt[3][1024*1024] | q[4096*1024] | k | vT
    unsigned short* wsb = (unsigned short*)d_ws;
    unsigned short* wt  = wsb;
    unsigned short* qp  = wsb + (size_t)3 * 1048576u;
    unsigned short* kp  = qp + 4194304u;
    unsigned short* vTp = kp + 4194304u;

    wt_kernel<<<dim3(16, 16, 3), 256, 0, stream>>>(WQ, WK, WV, wt);
    proj_kernel<<<dim3(8, 32, 3), 256, 0, stream>>>(Q_seq, K_seq, V_seq, wt, qp, kp, vTp);
    attn_kernel<<<dim3(16, 32), 256, 0, stream>>>(qp, kp, vTp, Q_len, V_len, outp);
}

// Round 2
// 198.072 us; speedup vs baseline: 1.2839x; 1.2839x over previous
//
#include <hip/hip_runtime.h>

// MultiHeadAttn: B=2, T=2048, D=1024, H=16, dh=64
// inputs: Q_seq,K_seq,V_seq [2,2048,1024] f32; Q_len,V_len [2,1] i32; WQ,WK,WV [1024,1024] f32
// output: [2,2048,1024] f32

using short8   = __attribute__((ext_vector_type(8))) short;
using floatx4  = __attribute__((ext_vector_type(4))) float;
using ushort4v = __attribute__((ext_vector_type(4))) unsigned short;

__device__ __forceinline__ unsigned short f2bf(float f) {
    unsigned int u = __builtin_bit_cast(unsigned int, f);
    u += 0x7fffu + ((u >> 16) & 1u);   // round-to-nearest-even
    return (unsigned short)(u >> 16);
}

// ---------------------------------------------------------------------------
// Kernel 1: W [1024][1024] f32  ->  W^T [1024][1024] bf16 (z = 0,1,2)
// ---------------------------------------------------------------------------
__global__ __launch_bounds__(256) void wt_kernel(
    const float* __restrict__ W0, const float* __restrict__ W1,
    const float* __restrict__ W2, unsigned short* __restrict__ out)
{
    __shared__ float tile[64][65];
    int z = blockIdx.z;
    const float* W = (z == 0) ? W0 : ((z == 1) ? W1 : W2);
    unsigned short* O = out + (size_t)z * 1048576u;
    int r0 = blockIdx.y * 64, c0 = blockIdx.x * 64;
    int t = threadIdx.x;
#pragma unroll
    for (int i = 0; i < 16; i++) {
        int idx = t + i * 256; int r = idx >> 6, c = idx & 63;
        tile[r][c] = W[(size_t)(r0 + r) * 1024 + c0 + c];
    }
    __syncthreads();
#pragma unroll
    for (int i = 0; i < 16; i++) {
        int idx = t + i * 256; int c = idx >> 6, r = idx & 63;
        O[(size_t)(c0 + c) * 1024 + r0 + r] = f2bf(tile[r][c]);
    }
}

// ---------------------------------------------------------------------------
// Kernel 2: projection GEMM  C[4096,1024] = A[4096,1024] @ W[1024,1024]
//   z=0 -> q (row-major bf16), z=1 -> k (row-major bf16),
//   z=2 -> vT layout [(b*1024 + h*64+d)][t] bf16
// ---------------------------------------------------------------------------
__global__ __launch_bounds__(256) void proj_kernel(
    const float* __restrict__ Qs, const float* __restrict__ Ks,
    const float* __restrict__ Vs, const unsigned short* __restrict__ wt,
    unsigned short* __restrict__ q, unsigned short* __restrict__ k,
    unsigned short* __restrict__ vT)
{
    __shared__ alignas(16) unsigned short As[128][40];
    __shared__ alignas(16) unsigned short Bs[128][40];

    int z = blockIdx.z;
    const float* A = (z == 0) ? Qs : ((z == 1) ? Ks : Vs);
    const unsigned short* Bt = wt + (size_t)z * 1048576u;

    int tid = threadIdx.x;
    int m0 = blockIdx.y * 128, n0 = blockIdx.x * 128;
    int w = tid >> 6, lane = tid & 63, g = lane >> 4, lr = lane & 15;
    int wr = w >> 1, wc = w & 1;

    floatx4 acc[4][4];
#pragma unroll
    for (int m = 0; m < 4; m++)
#pragma unroll
        for (int n = 0; n < 4; n++) acc[m][n] = floatx4{0.f, 0.f, 0.f, 0.f};

    int arow = tid >> 1, ahalf = tid & 1;

    for (int kb = 0; kb < 1024; kb += 32) {
        // stage A (fp32 -> bf16): 128x32
        {
            const float* p = A + (size_t)(m0 + arow) * 1024 + kb + ahalf * 16;
            float f[16];
#pragma unroll
            for (int i = 0; i < 4; i++) {
                float4 v = *reinterpret_cast<const float4*>(p + i * 4);
                f[i * 4 + 0] = v.x; f[i * 4 + 1] = v.y;
                f[i * 4 + 2] = v.z; f[i * 4 + 3] = v.w;
            }
            short8 h0, h1;
#pragma unroll
            for (int j = 0; j < 8; j++) h0[j] = (short)f2bf(f[j]);
#pragma unroll
            for (int j = 0; j < 8; j++) h1[j] = (short)f2bf(f[8 + j]);
            *reinterpret_cast<short8*>(&As[arow][ahalf * 16]) = h0;
            *reinterpret_cast<short8*>(&As[arow][ahalf * 16 + 8]) = h1;
        }
        // stage B^T (bf16 copy): 128 rows x 32 k
#pragma unroll
        for (int i = 0; i < 2; i++) {
            int ci = tid + i * 256; int row = ci >> 2, piece = ci & 3;
            *reinterpret_cast<short8*>(&Bs[row][piece * 8]) =
                *reinterpret_cast<const short8*>(Bt + (size_t)(n0 + row) * 1024 + kb + piece * 8);
        }
        __syncthreads();

        short8 af[4], bf[4];
#pragma unroll
        for (int m = 0; m < 4; m++)
            af[m] = *reinterpret_cast<const short8*>(&As[wr * 64 + m * 16 + lr][g * 8]);
#pragma unroll
        for (int n = 0; n < 4; n++)
            bf[n] = *reinterpret_cast<const short8*>(&Bs[wc * 64 + n * 16 + lr][g * 8]);
#pragma unroll
        for (int m = 0; m < 4; m++)
#pragma unroll
            for (int n = 0; n < 4; n++)
                acc[m][n] = __builtin_amdgcn_mfma_f32_16x16x32_bf16(af[m], bf[n], acc[m][n], 0, 0, 0);
        __syncthreads();
    }

    // epilogue
    if (z < 2) {
        unsigned short* out = (z == 0) ? q : k;
#pragma unroll
        for (int m = 0; m < 4; m++) {
            int row0 = m0 + wr * 64 + m * 16 + g * 4;
#pragma unroll
            for (int n = 0; n < 4; n++) {
                int col = n0 + wc * 64 + n * 16 + lr;
#pragma unroll
                for (int r = 0; r < 4; r++)
                    out[(size_t)(row0 + r) * 1024 + col] = f2bf(acc[m][n][r]);
            }
        }
    } else {
#pragma unroll
        for (int m = 0; m < 4; m++) {
            int row0 = m0 + wr * 64 + m * 16 + g * 4;
            int bb = row0 >> 11, t0 = row0 & 2047;
#pragma unroll
            for (int n = 0; n < 4; n++) {
                int col = n0 + wc * 64 + n * 16 + lr;
                ushort4v pk;
#pragma unroll
                for (int r = 0; r < 4; r++) pk[r] = f2bf(acc[m][n][r]);
                *reinterpret_cast<ushort4v*>(vT + (size_t)(bb * 1024 + col) * 2048 + t0) = pk;
            }
        }
    }
}

// ---------------------------------------------------------------------------
// Kernel 3: flash attention.
// grid 1024 blocks (32 q-tiles x 32 bh, XCD-swizzled), 256 threads.
// Each wave owns 16 q rows. KVBLK=64. Async reg-prefetch of next K/V tile.
// Softmax in raw-mfma domain (scale folded into exp2 constant).
// ---------------------------------------------------------------------------
__global__ __launch_bounds__(256, 4) void attn_kernel(
    const unsigned short* __restrict__ q, const unsigned short* __restrict__ k,
    const unsigned short* __restrict__ vT, const int* __restrict__ Q_len,
    const int* __restrict__ V_len, float* __restrict__ out)
{
    __shared__ alignas(16) unsigned short ks[64][72];
    __shared__ alignas(16) unsigned short vs[64][72];
    __shared__ alignas(16) unsigned short ps[4][16][72];

    int tid = threadIdx.x, w = tid >> 6, lane = tid & 63, g = lane >> 4, lr = lane & 15;
    // XCD swizzle: 8 XCDs x 128 blocks; each XCD owns 4 consecutive bh values
    int blk = blockIdx.x;
    int swz = (blk & 7) * 128 + (blk >> 3);
    int bh = swz >> 5, qtil = swz & 31;
    int b = bh >> 4, h = bh & 15;
    int qlen = Q_len[b], vlen = V_len[b];
    int qrow0 = qtil * 64 + w * 16;

    // Q fragments (A-operand), held for the whole kernel
    short8 qf[2];
    {
        const unsigned short* qp = q + (size_t)(b * 2048 + qrow0 + lr) * 1024 + h * 64;
        qf[0] = *reinterpret_cast<const short8*>(qp + g * 8);
        qf[1] = *reinterpret_cast<const short8*>(qp + 32 + g * 8);
    }

    floatx4 of[4];
    float m_r[4], l_r[4];
#pragma unroll
    for (int db = 0; db < 4; db++) of[db] = floatx4{0.f, 0.f, 0.f, 0.f};
#pragma unroll
    for (int r = 0; r < 4; r++) { m_r[r] = -3.0e38f; l_r[r] = 0.f; }

    // staging: each thread owns row=tid>>2 (0..63), 16 contiguous elems at (tid&3)*16
    int srow = tid >> 2, spc = (tid & 3) * 16;
    const unsigned short* kbase = k + ((size_t)(b * 2048 + srow) * 1024) + h * 64 + spc;
    const unsigned short* vbase = vT + ((size_t)(b * 1024 + h * 64 + srow) * 2048) + spc;

    short8 rk0, rk1, rv0, rv1;
    rk0 = *reinterpret_cast<const short8*>(kbase);
    rk1 = *reinterpret_cast<const short8*>(kbase + 8);
    rv0 = *reinterpret_cast<const short8*>(vbase);
    rv1 = *reinterpret_cast<const short8*>(vbase + 8);

    const float CEXP = 0.18033688011112042f;   // 0.125 * log2(e)
    int odd = lane & 1;

    for (int it = 0; it < 32; ++it) {
        int kt = it * 64;
        __syncthreads();
        *reinterpret_cast<short8*>(&ks[srow][spc])     = rk0;
        *reinterpret_cast<short8*>(&ks[srow][spc + 8]) = rk1;
        *reinterpret_cast<short8*>(&vs[srow][spc])     = rv0;
        *reinterpret_cast<short8*>(&vs[srow][spc + 8]) = rv1;
        __syncthreads();
        if (it < 31) {   // async prefetch next tile; latency hidden under compute
            const unsigned short* kp = kbase + (size_t)(kt + 64) * 1024;
            rk0 = *reinterpret_cast<const short8*>(kp);
            rk1 = *reinterpret_cast<const short8*>(kp + 8);
            const unsigned short* vp = vbase + kt + 64;
            rv0 = *reinterpret_cast<const short8*>(vp);
            rv1 = *reinterpret_cast<const short8*>(vp + 8);
        }

        // ---- S = Q K^T (raw a-domain; mask = -8e12 so 0.125*a matches ref)
        floatx4 sv[4];
        {
            short8 kf[4][2];
#pragma unroll
            for (int kb = 0; kb < 4; kb++)
#pragma unroll
                for (int kc = 0; kc < 2; kc++)
                    kf[kb][kc] = *reinterpret_cast<const short8*>(&ks[kb * 16 + lr][kc * 32 + g * 8]);
#pragma unroll
            for (int kb = 0; kb < 4; kb++) {
                floatx4 a = floatx4{0.f, 0.f, 0.f, 0.f};
                a = __builtin_amdgcn_mfma_f32_16x16x32_bf16(qf[0], kf[kb][0], a, 0, 0, 0);
                a = __builtin_amdgcn_mfma_f32_16x16x32_bf16(qf[1], kf[kb][1], a, 0, 0, 0);
                float pen = ((kt + kb * 16 + lr) >= vlen) ? -8.0e12f : 0.f;
#pragma unroll
                for (int r = 0; r < 4; r++) sv[kb][r] = a[r] + pen;
            }
        }

        // ---- online softmax: max reduce across the 16-lane col group
        float lm[4];
#pragma unroll
        for (int r = 0; r < 4; r++)
            lm[r] = fmaxf(fmaxf(sv[0][r], sv[1][r]), fmaxf(sv[2][r], sv[3][r]));
#pragma unroll
        for (int off = 8; off >= 1; off >>= 1)
#pragma unroll
            for (int r = 0; r < 4; r++)
                lm[r] = fmaxf(lm[r], __shfl_xor(lm[r], off, 16));

        float p[4][4];
#pragma unroll
        for (int r = 0; r < 4; r++) {
            bool up = lm[r] > m_r[r];
            float mn = up ? lm[r] : m_r[r];
            float al = up ? __builtin_amdgcn_exp2f((m_r[r] - mn) * CEXP) : 1.0f;
            m_r[r] = mn;
            float nmc = -mn * CEXP;
#pragma unroll
            for (int kb = 0; kb < 4; kb++)
                p[kb][r] = __builtin_amdgcn_exp2f(fmaf(sv[kb][r], CEXP, nmc));
            float rs = (p[0][r] + p[1][r]) + (p[2][r] + p[3][r]);
            l_r[r] = l_r[r] * al + rs;             // lane-partial; reduced in epilogue
#pragma unroll
            for (int db = 0; db < 4; db++) of[db][r] *= al;
        }

        // ---- pack P (bf16 pairs) into per-wave LDS; even lanes rows {0,1}, odd rows {2,3}
        {
            int rbase = g * 4 + (odd ? 2 : 0);
            int cp = (lr & ~1);
#pragma unroll
            for (int kb = 0; kb < 4; kb++) {
                float o0 = __shfl_xor(p[kb][0], 1);
                float o1 = __shfl_xor(p[kb][1], 1);
                float o2 = __shfl_xor(p[kb][2], 1);
                float o3 = __shfl_xor(p[kb][3], 1);
                float loA = odd ? o2 : p[kb][0];
                float hiA = odd ? p[kb][2] : o0;
                float loB = odd ? o3 : p[kb][1];
                float hiB = odd ? p[kb][3] : o1;
                unsigned int dA, dB;
                asm("v_cvt_pk_bf16_f32 %0, %1, %2" : "=v"(dA) : "v"(loA), "v"(hiA));
                asm("v_cvt_pk_bf16_f32 %0, %1, %2" : "=v"(dB) : "v"(loB), "v"(hiB));
                *reinterpret_cast<unsigned int*>(&ps[w][rbase][kb * 16 + cp])     = dA;
                *reinterpret_cast<unsigned int*>(&ps[w][rbase + 1][kb * 16 + cp]) = dB;
            }
        }

        // ---- PV: O += P @ V
        {
            short8 pf[2], vf[4][2];
            pf[0] = *reinterpret_cast<const short8*>(&ps[w][lr][g * 8]);
            pf[1] = *reinterpret_cast<const short8*>(&ps[w][lr][32 + g * 8]);
#pragma unroll
            for (int db = 0; db < 4; db++)
#pragma unroll
                for (int kc = 0; kc < 2; kc++)
                    vf[db][kc] = *reinterpret_cast<const short8*>(&vs[db * 16 + lr][kc * 32 + g * 8]);
#pragma unroll
            for (int db = 0; db < 4; db++) {
                of[db] = __builtin_amdgcn_mfma_f32_16x16x32_bf16(pf[0], vf[db][0], of[db], 0, 0, 0);
                of[db] = __builtin_amdgcn_mfma_f32_16x16x32_bf16(pf[1], vf[db][1], of[db], 0, 0, 0);
            }
        }
    }

    // epilogue: reduce l across the 16-lane group, apply q-len mask, write fp32
#pragma unroll
    for (int off = 8; off >= 1; off >>= 1)
#pragma unroll
        for (int r = 0; r < 4; r++)
            l_r[r] += __shfl_xor(l_r[r], off, 16);

#pragma unroll
    for (int r = 0; r < 4; r++) {
        int qrow = qrow0 + g * 4 + r;
        float qm = (qrow < qlen) ? (1.f / l_r[r]) : 0.f;
#pragma unroll
        for (int db = 0; db < 4; db++)
            out[(size_t)(b * 2048 + qrow) * 1024 + h * 64 + db * 16 + lr] = of[db][r] * qm;
    }
}

// ---------------------------------------------------------------------------
extern "C" void kernel_launch(void* const* d_in, const int* in_sizes, int n_in,
                              void* d_out, int out_size, void* d_ws, size_t ws_size,
                              hipStream_t stream)
{
    const float* Q_seq = (const float*)d_in[0];
    const float* K_seq = (const float*)d_in[1];
    const float* V_seq = (const float*)d_in[2];
    const int*   Q_len = (const int*)d_in[3];
    const int*   V_len = (const int*)d_in[4];
    const float* WQ    = (const float*)d_in[5];
    const float* WK    = (const float*)d_in[6];
    const float* WV    = (const float*)d_in[7];
    float* outp = (float*)d_out;

    // workspace layout (bf16 elems): Wt[3][1024*1024] | q[4096*1024] | k | vT
    unsigned short* wsb = (unsigned short*)d_ws;
    unsigned short* wt  = wsb;
    unsigned short* qp  = wsb + (size_t)3 * 1048576u;
    unsigned short* kp  = qp + 4194304u;
    unsigned short* vTp = kp + 4194304u;

    wt_kernel<<<dim3(16, 16, 3), 256, 0, stream>>>(WQ, WK, WV, wt);
    proj_kernel<<<dim3(8, 32, 3), 256, 0, stream>>>(Q_seq, K_seq, V_seq, wt, qp, kp, vTp);
    attn_kernel<<<dim3(1024), 256, 0, stream>>>(qp, kp, vTp, Q_len, V_len, outp);
}

// Round 3
// 79.655 us; speedup vs baseline: 3.1927x; 2.4866x over previous
//
#include <hip/hip_runtime.h>

// MultiHeadAttn: B=2, T=2048, D=1024, H=16, dh=64
// inputs: Q_seq,K_seq,V_seq [2,2048,1024] f32; Q_len,V_len [2,1] i32; WQ,WK,WV [1024,1024] f32
// output: [2,2048,1024] f32

using short8   = __attribute__((ext_vector_type(8))) short;
using floatx4  = __attribute__((ext_vector_type(4))) float;
using floatx16 = __attribute__((ext_vector_type(16))) float;
using uintx4   = __attribute__((ext_vector_type(4))) unsigned int;
using ushort4v = __attribute__((ext_vector_type(4))) unsigned short;

__device__ __forceinline__ unsigned short f2bf(float f) {
    unsigned int u = __builtin_bit_cast(unsigned int, f);
    u += 0x7fffu + ((u >> 16) & 1u);   // round-to-nearest-even
    return (unsigned short)(u >> 16);
}

// ---------------------------------------------------------------------------
// Kernel 0: fp32 -> bf16 convert of Q_seq/K_seq/V_seq rows that are needed.
// grid (4096, 3), 256 thr, 4 elems/thr (one row per block).
// ---------------------------------------------------------------------------
__global__ __launch_bounds__(256) void cvt_kernel(
    const float* __restrict__ Qs, const float* __restrict__ Ks,
    const float* __restrict__ Vs, const int* __restrict__ Qlen,
    const int* __restrict__ Vlen, unsigned short* __restrict__ abf)
{
    int z = blockIdx.y, row = blockIdx.x;
    int b = row >> 11, rib = row & 2047;
    int ql = Qlen[b]; int vl = Vlen[b]; int vle = vl ? vl : 2048;
    int lim = (z == 0) ? ((ql + 127) & ~127) : ((vle + 127) & ~127);
    if (rib >= lim) return;
    const float* src = (z == 0) ? Qs : ((z == 1) ? Ks : Vs);
    int t = threadIdx.x;
    float4 v = *reinterpret_cast<const float4*>(src + (size_t)row * 1024 + t * 4);
    ushort4v o;
    o[0] = f2bf(v.x); o[1] = f2bf(v.y); o[2] = f2bf(v.z); o[3] = f2bf(v.w);
    *reinterpret_cast<ushort4v*>(abf + (size_t)z * 4194304u + (size_t)row * 1024 + t * 4) = o;
}

// ---------------------------------------------------------------------------
// Kernel 1: W [1024][1024] f32  ->  W^T [1024][1024] bf16 (z = 0,1,2)
// ---------------------------------------------------------------------------
__global__ __launch_bounds__(256) void wt_kernel(
    const float* __restrict__ W0, const float* __restrict__ W1,
    const float* __restrict__ W2, unsigned short* __restrict__ out)
{
    __shared__ float tile[64][65];
    int z = blockIdx.z;
    const float* W = (z == 0) ? W0 : ((z == 1) ? W1 : W2);
    unsigned short* O = out + (size_t)z * 1048576u;
    int r0 = blockIdx.y * 64, c0 = blockIdx.x * 64;
    int t = threadIdx.x;
#pragma unroll
    for (int i = 0; i < 16; i++) {
        int idx = t + i * 256; int r = idx >> 6, c = idx & 63;
        tile[r][c] = W[(size_t)(r0 + r) * 1024 + c0 + c];
    }
    __syncthreads();
#pragma unroll
    for (int i = 0; i < 16; i++) {
        int idx = t + i * 256; int c = idx >> 6, r = idx & 63;
        O[(size_t)(c0 + c) * 1024 + r0 + r] = f2bf(tile[r][c]);
    }
}

// ---------------------------------------------------------------------------
// Kernel 2: projection GEMM  C[4096,1024] = A[4096,1024] @ W[1024,1024]
//   z=0 -> q (row-major bf16), z=1 -> k (row-major bf16),
//   z=2 -> vT layout [(b*1024 + h*64+d)][t] bf16
// 128x128 tile, BK=64, 4 waves (2x2), reg-prefetch double buffer, row-skip.
// PRECVT: A already bf16 in abf; else convert fp32 in staging.
// ---------------------------------------------------------------------------
template <bool PRECVT>
__global__ __launch_bounds__(256) void proj_kernel(
    const float* __restrict__ Qs, const float* __restrict__ Ks,
    const float* __restrict__ Vs, const unsigned short* __restrict__ abf,
    const unsigned short* __restrict__ wt,
    const int* __restrict__ Qlen, const int* __restrict__ Vlen,
    unsigned short* __restrict__ q, unsigned short* __restrict__ k,
    unsigned short* __restrict__ vT)
{
    __shared__ alignas(16) unsigned short As[128][72];
    __shared__ alignas(16) unsigned short Bs[128][72];

    int z = blockIdx.z;
    int tid = threadIdx.x;
    int m0 = blockIdx.y * 128, n0 = blockIdx.x * 128;
    int b = m0 >> 11, rib = m0 & 2047;
    int ql = Qlen[b]; int vl = Vlen[b]; int vle = vl ? vl : 2048;
    int lim = (z == 0) ? ((ql + 127) & ~127) : ((vle + 127) & ~127);
    if (rib >= lim) return;

    const float* Af = (z == 0) ? Qs : ((z == 1) ? Ks : Vs);
    const unsigned short* Ab = abf + (size_t)z * 4194304u;
    const unsigned short* Bt = wt + (size_t)z * 1048576u;

    int w = tid >> 6, lane = tid & 63, g = lane >> 4, lr = lane & 15;
    int wr = w >> 1, wc = w & 1;

    floatx4 acc[4][4];
#pragma unroll
    for (int m = 0; m < 4; m++)
#pragma unroll
        for (int n = 0; n < 4; n++) {
#pragma unroll
            for (int r = 0; r < 4; r++) acc[m][n][r] = 0.f;
        }

    int srow = tid >> 1, scol = (tid & 1) * 32;

    // prefetch registers
    short8 pa[4], pb[4];
    float4 fa[8];

    // initial load (kb = 0)
    if constexpr (PRECVT) {
#pragma unroll
        for (int i = 0; i < 4; i++)
            pa[i] = *reinterpret_cast<const short8*>(Ab + (size_t)(m0 + srow) * 1024 + scol + i * 8);
    } else {
#pragma unroll
        for (int i = 0; i < 8; i++)
            fa[i] = *reinterpret_cast<const float4*>(Af + (size_t)(m0 + srow) * 1024 + scol + i * 4);
    }
#pragma unroll
    for (int i = 0; i < 4; i++)
        pb[i] = *reinterpret_cast<const short8*>(Bt + (size_t)(n0 + srow) * 1024 + scol + i * 8);

    for (int kb = 0; kb < 1024; kb += 64) {
        __syncthreads();
        if constexpr (PRECVT) {
#pragma unroll
            for (int i = 0; i < 4; i++)
                *reinterpret_cast<short8*>(&As[srow][scol + i * 8]) = pa[i];
        } else {
#pragma unroll
            for (int i = 0; i < 4; i++) {
                short8 h;
                h[0] = (short)f2bf(fa[2*i].x);   h[1] = (short)f2bf(fa[2*i].y);
                h[2] = (short)f2bf(fa[2*i].z);   h[3] = (short)f2bf(fa[2*i].w);
                h[4] = (short)f2bf(fa[2*i+1].x); h[5] = (short)f2bf(fa[2*i+1].y);
                h[6] = (short)f2bf(fa[2*i+1].z); h[7] = (short)f2bf(fa[2*i+1].w);
                *reinterpret_cast<short8*>(&As[srow][scol + i * 8]) = h;
            }
        }
#pragma unroll
        for (int i = 0; i < 4; i++)
            *reinterpret_cast<short8*>(&Bs[srow][scol + i * 8]) = pb[i];
        __syncthreads();

        if (kb + 64 < 1024) {
            if constexpr (PRECVT) {
#pragma unroll
                for (int i = 0; i < 4; i++)
                    pa[i] = *reinterpret_cast<const short8*>(Ab + (size_t)(m0 + srow) * 1024 + kb + 64 + scol + i * 8);
            } else {
#pragma unroll
                for (int i = 0; i < 8; i++)
                    fa[i] = *reinterpret_cast<const float4*>(Af + (size_t)(m0 + srow) * 1024 + kb + 64 + scol + i * 4);
            }
#pragma unroll
            for (int i = 0; i < 4; i++)
                pb[i] = *reinterpret_cast<const short8*>(Bt + (size_t)(n0 + srow) * 1024 + kb + 64 + scol + i * 8);
        }

#pragma unroll
        for (int kc = 0; kc < 2; kc++) {
            short8 af[4], bf[4];
#pragma unroll
            for (int m = 0; m < 4; m++)
                af[m] = *reinterpret_cast<const short8*>(&As[wr * 64 + m * 16 + lr][kc * 32 + g * 8]);
#pragma unroll
            for (int n = 0; n < 4; n++)
                bf[n] = *reinterpret_cast<const short8*>(&Bs[wc * 64 + n * 16 + lr][kc * 32 + g * 8]);
#pragma unroll
            for (int m = 0; m < 4; m++)
#pragma unroll
                for (int n = 0; n < 4; n++)
                    acc[m][n] = __builtin_amdgcn_mfma_f32_16x16x32_bf16(af[m], bf[n], acc[m][n], 0, 0, 0);
        }
    }

    // epilogue
    if (z < 2) {
        unsigned short* outp = (z == 0) ? q : k;
#pragma unroll
        for (int m = 0; m < 4; m++) {
            int row0 = m0 + wr * 64 + m * 16 + g * 4;
#pragma unroll
            for (int n = 0; n < 4; n++) {
                int col = n0 + wc * 64 + n * 16 + lr;
#pragma unroll
                for (int r = 0; r < 4; r++)
                    outp[(size_t)(row0 + r) * 1024 + col] = f2bf(acc[m][n][r]);
            }
        }
    } else {
#pragma unroll
        for (int m = 0; m < 4; m++) {
            int row0 = m0 + wr * 64 + m * 16 + g * 4;
            int bb = row0 >> 11, t0 = row0 & 2047;
#pragma unroll
            for (int n = 0; n < 4; n++) {
                int col = n0 + wc * 64 + n * 16 + lr;
                ushort4v pk;
#pragma unroll
                for (int r = 0; r < 4; r++) pk[r] = f2bf(acc[m][n][r]);
                *reinterpret_cast<ushort4v*>(vT + (size_t)(bb * 1024 + col) * 2048 + t0) = pk;
            }
        }
    }
}

// ---------------------------------------------------------------------------
// Kernel 3: flash attention, 32x32 swapped-QK, in-register softmax + P.
// grid 1024 blocks (XCD-swizzled: 32 bh x 32 qtiles), 128 threads (2 waves).
// Each wave: 32 q rows. Block q-skip; kt loop bounded by ceil(vle/64).
// ---------------------------------------------------------------------------
__global__ __launch_bounds__(128, 2) void attn_kernel(
    const unsigned short* __restrict__ q, const unsigned short* __restrict__ k,
    const unsigned short* __restrict__ vT, const int* __restrict__ Qlen,
    const int* __restrict__ Vlen, float* __restrict__ out)
{
    __shared__ alignas(16) unsigned short ks[64][72];   // [key][dh]
    __shared__ alignas(16) unsigned short vs[64][72];   // [d][key]

    int tid = threadIdx.x;
    int w = tid >> 6, lane = tid & 63;
    int j = lane & 31, hi = lane >> 5;

    int blk = blockIdx.x, xcd = blk & 7, idx = blk >> 3;
    int bh = xcd * 4 + (idx >> 5), qtile = idx & 31;
    int b = bh >> 4, h = bh & 15;
    int qlen = Qlen[b]; int vl = Vlen[b]; int vle = vl ? vl : 2048;
    int qrow0 = qtile * 64 + w * 32;

    if (qtile * 64 >= qlen) {   // whole block masked -> zeros (block-uniform)
        int zr = qtile * 64 + (tid >> 1);
        float* p = out + (size_t)(b * 2048 + zr) * 1024 + h * 64 + (tid & 1) * 32;
        float4 z4; z4.x = 0.f; z4.y = 0.f; z4.z = 0.f; z4.w = 0.f;
#pragma unroll
        for (int s = 0; s < 8; s++) reinterpret_cast<float4*>(p)[s] = z4;
        return;
    }

    // Q fragments: B-operand, lane holds Q[q=qrow0+j][c*16 + hi*8 + 0..7]
    short8 qf[4];
    {
        const unsigned short* qp = q + (size_t)(b * 2048 + qrow0 + j) * 1024 + h * 64 + hi * 8;
#pragma unroll
        for (int c = 0; c < 4; c++) qf[c] = *reinterpret_cast<const short8*>(qp + c * 16);
    }

    floatx16 O0, O1;
#pragma unroll
    for (int t = 0; t < 16; t++) { O0[t] = 0.f; O1[t] = 0.f; }
    float m_r = -3.0e38f, l_r = 0.f;

    int nt = (vle + 63) >> 6;

    // staging: thread owns row tid>>1, 32 bf16 at (tid&1)*32
    int srow = tid >> 1, scol = (tid & 1) * 32;
    const unsigned short* kg = k + (size_t)(b * 2048 + srow) * 1024 + h * 64 + scol;
    const unsigned short* vg = vT + (size_t)(b * 1024 + h * 64 + srow) * 2048 + scol;
    short8 pk[4], pv[4];
#pragma unroll
    for (int i = 0; i < 4; i++) {
        pk[i] = *reinterpret_cast<const short8*>(kg + i * 8);
        pv[i] = *reinterpret_cast<const short8*>(vg + i * 8);
    }

    const float CEXP = 0.18033688011112042f;   // 0.125 * log2(e)

    for (int it = 0; it < nt; ++it) {
        int kt = it * 64;
        __syncthreads();
#pragma unroll
        for (int i = 0; i < 4; i++) {
            *reinterpret_cast<short8*>(&ks[srow][scol + i * 8]) = pk[i];
            *reinterpret_cast<short8*>(&vs[srow][scol + i * 8]) = pv[i];
        }
        __syncthreads();
        if (it + 1 < nt) {
            const unsigned short* kg2 = kg + (size_t)(kt + 64) * 1024;
            const unsigned short* vg2 = vg + (kt + 64);
#pragma unroll
            for (int i = 0; i < 4; i++) {
                pk[i] = *reinterpret_cast<const short8*>(kg2 + i * 8);
                pv[i] = *reinterpret_cast<const short8*>(vg2 + i * 8);
            }
        }

        // ---- QK^T (swapped): D[key][q], col=lane&31=q, row=(t&3)+8*(t>>2)+4*hi
        floatx16 s0, s1;
#pragma unroll
        for (int t = 0; t < 16; t++) { s0[t] = 0.f; s1[t] = 0.f; }
        {
            short8 kf0[4], kf1[4];
#pragma unroll
            for (int c = 0; c < 4; c++) {
                kf0[c] = *reinterpret_cast<const short8*>(&ks[j][c * 16 + hi * 8]);
                kf1[c] = *reinterpret_cast<const short8*>(&ks[32 + j][c * 16 + hi * 8]);
            }
#pragma unroll
            for (int c = 0; c < 4; c++) {
                s0 = __builtin_amdgcn_mfma_f32_32x32x16_bf16(kf0[c], qf[c], s0, 0, 0, 0);
                s1 = __builtin_amdgcn_mfma_f32_32x32x16_bf16(kf1[c], qf[c], s1, 0, 0, 0);
            }
        }

        if (kt + 64 > vle) {   // boundary tile: mask keys >= vle (uniform branch)
#pragma unroll
            for (int t = 0; t < 16; t++) {
                int kl = (t & 3) + 8 * (t >> 2) + 4 * hi;
                if (kt + kl >= vle)      s0[t] = -8.0e12f;
                if (kt + 32 + kl >= vle) s1[t] = -8.0e12f;
            }
        }

        // ---- softmax (one stage per 64-key tile)
        float mx = s0[0];
#pragma unroll
        for (int t = 1; t < 16; t++) mx = fmaxf(mx, s0[t]);
#pragma unroll
        for (int t = 0; t < 16; t++) mx = fmaxf(mx, s1[t]);
        float lm = fmaxf(mx, __shfl_xor(mx, 32));

        if (__any(lm > m_r + 64.f)) {      // rescale only on significant growth
            float mn = fmaxf(m_r, lm);
            float al = __builtin_amdgcn_exp2f((m_r - mn) * CEXP);
            m_r = mn;
            l_r *= al;
#pragma unroll
            for (int t = 0; t < 16; t++) { O0[t] *= al; O1[t] *= al; }
        }
        float nm = -m_r * CEXP;
#pragma unroll
        for (int t = 0; t < 16; t++) {
            s0[t] = __builtin_amdgcn_exp2f(fmaf(s0[t], CEXP, nm));
            s1[t] = __builtin_amdgcn_exp2f(fmaf(s1[t], CEXP, nm));
        }
        float rs = 0.f;
#pragma unroll
        for (int t = 0; t < 16; t++) rs += s0[t] + s1[t];
        l_r += rs;

        // ---- P -> bf16 B-fragments via cvt_pk + permlane32_swap
        // source dword (kb, s, u) holds key-pair kp = 32*kb/2.. -> chunk c=2kb+(s>>1), slots {u, u+2}
        unsigned int pbw[4][4];
        {
            unsigned int D[4][2];
#pragma unroll
            for (int s = 0; s < 4; s++) {
                asm("v_cvt_pk_bf16_f32 %0, %1, %2" : "=v"(D[s][0]) : "v"(s0[4*s+0]), "v"(s0[4*s+1]));
                asm("v_cvt_pk_bf16_f32 %0, %1, %2" : "=v"(D[s][1]) : "v"(s0[4*s+2]), "v"(s0[4*s+3]));
            }
#pragma unroll
            for (int u = 0; u < 2; u++) {
                asm volatile("v_permlane32_swap_b32 %0, %1" : "+v"(D[0][u]), "+v"(D[1][u]));
                asm volatile("v_permlane32_swap_b32 %0, %1" : "+v"(D[2][u]), "+v"(D[3][u]));
                pbw[0][u] = D[0][u]; pbw[0][u + 2] = D[1][u];
                pbw[1][u] = D[2][u]; pbw[1][u + 2] = D[3][u];
            }
#pragma unroll
            for (int s = 0; s < 4; s++) {
                asm("v_cvt_pk_bf16_f32 %0, %1, %2" : "=v"(D[s][0]) : "v"(s1[4*s+0]), "v"(s1[4*s+1]));
                asm("v_cvt_pk_bf16_f32 %0, %1, %2" : "=v"(D[s][1]) : "v"(s1[4*s+2]), "v"(s1[4*s+3]));
            }
#pragma unroll
            for (int u = 0; u < 2; u++) {
                asm volatile("v_permlane32_swap_b32 %0, %1" : "+v"(D[0][u]), "+v"(D[1][u]));
                asm volatile("v_permlane32_swap_b32 %0, %1" : "+v"(D[2][u]), "+v"(D[3][u]));
                pbw[2][u] = D[0][u]; pbw[2][u + 2] = D[1][u];
                pbw[3][u] = D[2][u]; pbw[3][u + 2] = D[3][u];
            }
        }

        // ---- PV: O[d][q] += V^T x P, chunks c over 64 keys
        {
            short8 vf0[4], vf1[4];
#pragma unroll
            for (int c = 0; c < 4; c++) {
                vf0[c] = *reinterpret_cast<const short8*>(&vs[j][c * 16 + hi * 8]);
                vf1[c] = *reinterpret_cast<const short8*>(&vs[32 + j][c * 16 + hi * 8]);
            }
#pragma unroll
            for (int c = 0; c < 4; c++) {
                uintx4 pw; pw[0] = pbw[c][0]; pw[1] = pbw[c][1]; pw[2] = pbw[c][2]; pw[3] = pbw[c][3];
                short8 pf = __builtin_bit_cast(short8, pw);
                O0 = __builtin_amdgcn_mfma_f32_32x32x16_bf16(vf0[c], pf, O0, 0, 0, 0);
                O1 = __builtin_amdgcn_mfma_f32_32x32x16_bf16(vf1[c], pf, O1, 0, 0, 0);
            }
        }
    }

    // epilogue
    float lt = l_r + __shfl_xor(l_r, 32);
    int qrow = qrow0 + j;
    float qm = (qrow < qlen) ? (1.0f / lt) : 0.f;
    float* ob = out + (size_t)(b * 2048 + qrow) * 1024 + h * 64;
#pragma unroll
    for (int s = 0; s < 4; s++) {
        float4 oa, obv;
        oa.x = O0[4*s+0] * qm; oa.y = O0[4*s+1] * qm; oa.z = O0[4*s+2] * qm; oa.w = O0[4*s+3] * qm;
        obv.x = O1[4*s+0] * qm; obv.y = O1[4*s+1] * qm; obv.z = O1[4*s+2] * qm; obv.w = O1[4*s+3] * qm;
        *reinterpret_cast<float4*>(ob + 8 * s + 4 * hi) = oa;
        *reinterpret_cast<float4*>(ob + 32 + 8 * s + 4 * hi) = obv;
    }
}

// ---------------------------------------------------------------------------
extern "C" void kernel_launch(void* const* d_in, const int* in_sizes, int n_in,
                              void* d_out, int out_size, void* d_ws, size_t ws_size,
                              hipStream_t stream)
{
    const float* Q_seq = (const float*)d_in[0];
    const float* K_seq = (const float*)d_in[1];
    const float* V_seq = (const float*)d_in[2];
    const int*   Q_len = (const int*)d_in[3];
    const int*   V_len = (const int*)d_in[4];
    const float* WQ    = (const float*)d_in[5];
    const float* WK    = (const float*)d_in[6];
    const float* WV    = (const float*)d_in[7];
    float* outp = (float*)d_out;

    // ws layout (bf16 elems): wt[3*1M] | q[4M] | k[4M] | vT[4M] | abf[3*4M]
    unsigned short* wsb = (unsigned short*)d_ws;
    unsigned short* wt  = wsb;
    unsigned short* qp  = wsb + (size_t)3 * 1048576u;
    unsigned short* kp  = qp + 4194304u;
    unsigned short* vTp = kp + 4194304u;
    unsigned short* abf = vTp + 4194304u;

    size_t need = ((size_t)3 * 1048576u + 3u * 4194304u + (size_t)3 * 4194304u) * 2u;
    bool precvt = ws_size >= need;

    wt_kernel<<<dim3(16, 16, 3), 256, 0, stream>>>(WQ, WK, WV, wt);
    if (precvt) {
        cvt_kernel<<<dim3(4096, 3), 256, 0, stream>>>(Q_seq, K_seq, V_seq, Q_len, V_len, abf);
        proj_kernel<true><<<dim3(8, 32, 3), 256, 0, stream>>>(
            Q_seq, K_seq, V_seq, abf, wt, Q_len, V_len, qp, kp, vTp);
    } else {
        proj_kernel<false><<<dim3(8, 32, 3), 256, 0, stream>>>(
            Q_seq, K_seq, V_seq, nullptr, wt, Q_len, V_len, qp, kp, vTp);
    }
    attn_kernel<<<dim3(1024), 128, 0, stream>>>(qp, kp, vTp, Q_len, V_len, outp);
}